// Round 1
// baseline (258.604 us; speedup 1.0000x reference)
//
#include <hip/hip_runtime.h>

#define NROWS 8192
#define DIN   64
#define DMID  1024
#define DOUT  64
#define NDOM  4
#define PADROWS 8704   // 8192 + 4*128 upper bound on padded total
#define MAXTILES 68

typedef _Float16 half8 __attribute__((ext_vector_type(8)));
typedef _Float16 half4v __attribute__((ext_vector_type(4)));
typedef float floatx4 __attribute__((ext_vector_type(4)));

__device__ __forceinline__ void gload16(const void* g, void* l) {
  __builtin_amdgcn_global_load_lds((const __attribute__((address_space(1))) void*)g,
                                   (__attribute__((address_space(3))) void*)l, 16, 0, 0);
}

// ---------------- conversion kernels ----------------

__global__ void cast_f32_to_f16(const float* __restrict__ src, _Float16* __restrict__ dst, int n4) {
  int i = blockIdx.x * blockDim.x + threadIdx.x;
  if (i < n4) {
    float4 v = reinterpret_cast<const float4*>(src)[i];
    half4v o;
    o[0] = (_Float16)v.x; o[1] = (_Float16)v.y; o[2] = (_Float16)v.z; o[3] = (_Float16)v.w;
    reinterpret_cast<half4v*>(dst)[i] = o;
  }
}

// src: [batch][R][C] fp32  ->  dst: [batch][C][R] fp16   (R,C multiples of 64)
__global__ void transpose_cast(const float* __restrict__ src, _Float16* __restrict__ dst,
                               int R, int C) {
  const int b = blockIdx.z;
  src += (size_t)b * R * C;
  dst += (size_t)b * R * C;
  const int c0 = blockIdx.x * 64;
  const int r0 = blockIdx.y * 64;
  __shared__ float tile[64][65];
  const int t = threadIdx.x;
  const int x = t & 63;
  const int y4 = t >> 6;   // 0..3
#pragma unroll
  for (int i = 0; i < 16; ++i) {
    int r = y4 * 16 + i;
    tile[r][x] = src[(size_t)(r0 + r) * C + (c0 + x)];
  }
  __syncthreads();
#pragma unroll
  for (int i = 0; i < 16; ++i) {
    int c = y4 * 16 + i;
    dst[(size_t)(c0 + c) * R + (r0 + x)] = (_Float16)tile[x][c];
  }
}

// ---------------- routing setup ----------------
// meta[0]=T ; meta[8+t]=domain ; meta[80+t]=tile base row (sorted space) ; meta[160+t]=valid rows
__global__ void setup_kernel(const int* __restrict__ domains, int* __restrict__ meta,
                             int* __restrict__ sortpos, int* __restrict__ invperm) {
  __shared__ int cnt[NDOM];
  __shared__ int cur[NDOM];
  const int t = threadIdx.x;
  if (t < NDOM) cnt[t] = 0;
  __syncthreads();
  for (int i = t; i < NROWS; i += blockDim.x)
    atomicAdd(&cnt[domains[i]], 1);
  __syncthreads();
  if (t == 0) {
    int off = 0, T = 0;
    for (int d = 0; d < NDOM; ++d) {
      cur[d] = off;
      int c = cnt[d];
      int nt = (c + 127) >> 7;
      for (int k = 0; k < nt; ++k) {
        meta[8 + T]   = d;
        meta[80 + T]  = off + k * 128;
        int rem = c - k * 128;
        meta[160 + T] = rem > 128 ? 128 : rem;
        ++T;
      }
      off += nt * 128;
    }
    meta[0] = T;
  }
  __syncthreads();
  for (int i = t; i < NROWS; i += blockDim.x) {
    int d = domains[i];
    int p = atomicAdd(&cur[d], 1);
    sortpos[i] = p;
    invperm[p] = i;
  }
}

// ---------------- fused GEMM (+bias, +relu) ----------------
// A: [*, K] fp16 row-major; Bt: [Ntot][K] fp16 (W^T); bias fp32 length Ntot (per domain).
// IN_MODE 0: rowbase = blockIdx.y*128 (dense)
// IN_MODE 1: tile map routing (domain weights/bias, sorted rows)
// OUT_MODE 0: Ch[(rowbase+row)*ldC + col]
// OUT_MODE 1: Ch[sortpos[rowbase+row]*ldC + col]          (scatter into sorted buffer)
// OUT_MODE 2: Cf[invperm[rowbase+row]*ldC + col], fp32, only row<valid (final output)
template<int BN, int NKT, bool RELU, int IN_MODE, int OUT_MODE>
__global__ __launch_bounds__(256, 2)
void gemm_f16(const _Float16* __restrict__ A, const _Float16* __restrict__ Bt,
              const float* __restrict__ bias,
              _Float16* __restrict__ Ch, float* __restrict__ Cf,
              const int* __restrict__ meta, const int* __restrict__ sortpos,
              const int* __restrict__ invperm, int ldC) {
  constexpr int BM = 128, BK = 64;
  constexpr int K = NKT * BK;
  constexpr int NFN = BN / 32;           // frags per wave in N (4 for BN=128, 2 for BN=64)
  const int tid = threadIdx.x;
  const int lane = tid & 63, wv = tid >> 6;
  const int lr = lane & 15, lk = lane >> 4;
  const int wr = wv >> 1, wc = wv & 1;

  int rowbase, valid = BM;
  if constexpr (IN_MODE == 1) {
    const int T = meta[0];
    if ((int)blockIdx.y >= T) return;
    const int dom = meta[8 + blockIdx.y];
    rowbase = meta[80 + blockIdx.y];
    valid   = meta[160 + blockIdx.y];
    Bt   += (size_t)dom * ldC * K;
    bias += (size_t)dom * ldC;
  } else {
    rowbase = blockIdx.y * BM;
  }
  const int n0 = blockIdx.x * BN;

  __shared__ __align__(16) unsigned char sA[BM * BK * 2];  // 16 KB
  __shared__ __align__(16) unsigned char sB[BN * BK * 2];  // 16 or 8 KB

  floatx4 acc[4][NFN];
#pragma unroll
  for (int i = 0; i < 4; ++i)
#pragma unroll
    for (int j = 0; j < NFN; ++j)
      acc[i][j] = (floatx4){0.f, 0.f, 0.f, 0.f};

  const unsigned char* Ab = (const unsigned char*)A + (size_t)rowbase * K * 2;
  const unsigned char* Bb = (const unsigned char*)Bt + (size_t)n0 * K * 2;

  for (int kt = 0; kt < NKT; ++kt) {
    const int kbyte0 = kt * BK * 2;   // 128 B of K per row per tile
    // stage A: BM rows x 128B = 16 chunks of 1KB; wave wv -> chunks wv*4+i
#pragma unroll
    for (int i = 0; i < 4; ++i) {
      int lo = (wv * 4 + i) * 1024 + lane * 16;
      int row = lo >> 7;
      int kb = lo & 127;
      int gkb = kb ^ ((row & 7) << 4);   // inverse-swizzled source -> linear LDS dest
      gload16(Ab + (size_t)row * (K * 2) + kbyte0 + gkb, sA + lo);
    }
    // stage B: BN rows x 128B
#pragma unroll
    for (int i = 0; i < BN / 32; ++i) {
      int lo = (wv * (BN / 32) + i) * 1024 + lane * 16;
      int row = lo >> 7;
      int kb = lo & 127;
      int gkb = kb ^ ((row & 7) << 4);
      gload16(Bb + (size_t)row * (K * 2) + kbyte0 + gkb, sB + lo);
    }
    __syncthreads();   // compiler drains vmcnt before the barrier

#pragma unroll
    for (int kk = 0; kk < 2; ++kk) {
      half8 af[4], bf[NFN];
#pragma unroll
      for (int fm = 0; fm < 4; ++fm) {
        int row = wr * 64 + fm * 16 + lr;
        int kb = kk * 64 + lk * 16;
        int addr = row * 128 + (kb ^ ((row & 7) << 4));
        af[fm] = *(const half8*)(sA + addr);
      }
#pragma unroll
      for (int fn = 0; fn < NFN; ++fn) {
        int row = wc * (BN / 2) + fn * 16 + lr;
        int kb = kk * 64 + lk * 16;
        int addr = row * 128 + (kb ^ ((row & 7) << 4));
        bf[fn] = *(const half8*)(sB + addr);
      }
#pragma unroll
      for (int fm = 0; fm < 4; ++fm)
#pragma unroll
        for (int fn = 0; fn < NFN; ++fn)
          acc[fm][fn] = __builtin_amdgcn_mfma_f32_16x16x32_f16(af[fm], bf[fn], acc[fm][fn], 0, 0, 0);
    }
    __syncthreads();
  }

  // epilogue: bias (+relu), store
  const int colbase = n0 + wc * (BN / 2);
#pragma unroll
  for (int fn = 0; fn < NFN; ++fn) {
    const int col = colbase + fn * 16 + lr;
    const float bv = bias[col];
#pragma unroll
    for (int fm = 0; fm < 4; ++fm) {
      const int rl = wr * 64 + fm * 16 + lk * 4;
#pragma unroll
      for (int r = 0; r < 4; ++r) {
        float v = acc[fm][fn][r] + bv;
        if (RELU) v = v > 0.f ? v : 0.f;
        const int row = rl + r;
        if constexpr (OUT_MODE == 0) {
          Ch[(size_t)(rowbase + row) * ldC + col] = (_Float16)v;
        } else if constexpr (OUT_MODE == 1) {
          const int orow = sortpos[rowbase + row];
          Ch[(size_t)orow * ldC + col] = (_Float16)v;
        } else {
          if (row < valid) {
            const int orow = invperm[rowbase + row];
            Cf[(size_t)orow * ldC + col] = v;
          }
        }
      }
    }
  }
}

// ---------------- launch ----------------

extern "C" void kernel_launch(void* const* d_in, const int* in_sizes, int n_in,
                              void* d_out, int out_size, void* d_ws, size_t ws_size,
                              hipStream_t stream) {
  const float* X   = (const float*)d_in[0];
  const int* domains = (const int*)d_in[1];
  const float* W1  = (const float*)d_in[2];
  const float* b1  = (const float*)d_in[3];
  const float* W2  = (const float*)d_in[4];
  const float* b2  = (const float*)d_in[5];
  const float* W3  = (const float*)d_in[6];
  const float* b3  = (const float*)d_in[7];
  const float* W4  = (const float*)d_in[8];
  const float* b4  = (const float*)d_in[9];
  const float* BW1 = (const float*)d_in[10];
  const float* Bb1 = (const float*)d_in[11];
  const float* BW2 = (const float*)d_in[12];
  const float* Bb2 = (const float*)d_in[13];
  const float* BW3 = (const float*)d_in[14];
  const float* Bb3 = (const float*)d_in[15];
  const float* BW4 = (const float*)d_in[16];
  const float* Bb4 = (const float*)d_in[17];
  float* out = (float*)d_out;

  char* base = (char*)d_ws;
  size_t off = 0;
  auto alloc = [&](size_t bytes) -> void* {
    void* p = base + off;
    off = (off + bytes + 255) & ~(size_t)255;
    return p;
  };
  _Float16* Xh   = (_Float16*)alloc((size_t)NROWS * DIN * 2);
  _Float16* W1t  = (_Float16*)alloc((size_t)DMID * DIN * 2);
  _Float16* W2t  = (_Float16*)alloc((size_t)DMID * DMID * 2);
  _Float16* W3t  = (_Float16*)alloc((size_t)DMID * DMID * 2);
  _Float16* W4t  = (_Float16*)alloc((size_t)DMID * DMID * 2);
  _Float16* BW1t = (_Float16*)alloc((size_t)NDOM * DMID * DMID * 2);
  _Float16* BW2t = (_Float16*)alloc((size_t)NDOM * DMID * DMID * 2);
  _Float16* BW3t = (_Float16*)alloc((size_t)NDOM * DMID * DMID * 2);
  _Float16* BW4t = (_Float16*)alloc((size_t)NDOM * DOUT * DMID * 2);
  _Float16* bufA = (_Float16*)alloc((size_t)NROWS * DMID * 2);
  _Float16* bufS0= (_Float16*)alloc((size_t)PADROWS * DMID * 2);
  _Float16* bufS1= (_Float16*)alloc((size_t)PADROWS * DMID * 2);
  int* sortpos   = (int*)alloc((size_t)NROWS * 4);
  int* invperm   = (int*)alloc((size_t)PADROWS * 4);
  int* meta      = (int*)alloc(1024 * 4);

  // conversions
  cast_f32_to_f16<<<dim3((NROWS * DIN / 4) / 256), 256, 0, stream>>>(X, Xh, NROWS * DIN / 4);
  transpose_cast<<<dim3(DMID / 64, DIN / 64, 1),  256, 0, stream>>>(W1, W1t, DIN, DMID);
  transpose_cast<<<dim3(DMID / 64, DMID / 64, 1), 256, 0, stream>>>(W2, W2t, DMID, DMID);
  transpose_cast<<<dim3(DMID / 64, DMID / 64, 1), 256, 0, stream>>>(W3, W3t, DMID, DMID);
  transpose_cast<<<dim3(DMID / 64, DMID / 64, 1), 256, 0, stream>>>(W4, W4t, DMID, DMID);
  transpose_cast<<<dim3(DMID / 64, DMID / 64, NDOM), 256, 0, stream>>>(BW1, BW1t, DMID, DMID);
  transpose_cast<<<dim3(DMID / 64, DMID / 64, NDOM), 256, 0, stream>>>(BW2, BW2t, DMID, DMID);
  transpose_cast<<<dim3(DMID / 64, DMID / 64, NDOM), 256, 0, stream>>>(BW3, BW3t, DMID, DMID);
  transpose_cast<<<dim3(DOUT / 64, DMID / 64, NDOM), 256, 0, stream>>>(BW4, BW4t, DMID, DOUT);

  // routing + zero the padded sorted buffer (pad rows must be 0 entering branch stack)
  setup_kernel<<<1, 256, 0, stream>>>(domains, meta, sortpos, invperm);
  hipMemsetAsync(bufS0, 0, (size_t)PADROWS * DMID * 2, stream);

  // shared MLP
  gemm_f16<128, 1,  true, 0, 0><<<dim3(DMID / 128, NROWS / 128), 256, 0, stream>>>(
      Xh, W1t, b1, bufA, nullptr, nullptr, nullptr, nullptr, DMID);
  gemm_f16<128, 16, true, 0, 0><<<dim3(DMID / 128, NROWS / 128), 256, 0, stream>>>(
      bufA, W2t, b2, bufS1, nullptr, nullptr, nullptr, nullptr, DMID);
  gemm_f16<128, 16, true, 0, 0><<<dim3(DMID / 128, NROWS / 128), 256, 0, stream>>>(
      bufS1, W3t, b3, bufA, nullptr, nullptr, nullptr, nullptr, DMID);
  // layer 4: scatter rows into domain-sorted padded buffer
  gemm_f16<128, 16, true, 0, 1><<<dim3(DMID / 128, NROWS / 128), 256, 0, stream>>>(
      bufA, W4t, b4, bufS0, nullptr, nullptr, sortpos, nullptr, DMID);

  // branch MLP (routed, sorted space)
  gemm_f16<128, 16, true, 1, 0><<<dim3(DMID / 128, MAXTILES), 256, 0, stream>>>(
      bufS0, BW1t, Bb1, bufS1, nullptr, meta, nullptr, nullptr, DMID);
  gemm_f16<128, 16, true, 1, 0><<<dim3(DMID / 128, MAXTILES), 256, 0, stream>>>(
      bufS1, BW2t, Bb2, bufS0, nullptr, meta, nullptr, nullptr, DMID);
  gemm_f16<128, 16, true, 1, 0><<<dim3(DMID / 128, MAXTILES), 256, 0, stream>>>(
      bufS0, BW3t, Bb3, bufS1, nullptr, meta, nullptr, nullptr, DMID);
  // final layer: fp32 scatter to d_out, no relu
  gemm_f16<64, 16, false, 1, 2><<<dim3(1, MAXTILES), 256, 0, stream>>>(
      bufS1, BW4t, Bb4, nullptr, out, meta, nullptr, invperm, DOUT);
}